// Round 20
// baseline (113.057 us; speedup 1.0000x reference)
//
#include <hip/hip_runtime.h>

typedef unsigned short u16;
typedef unsigned int u32;
typedef __bf16 b16x8 __attribute__((ext_vector_type(8)));
typedef u16 u16x8 __attribute__((ext_vector_type(8)));
typedef float f32x4 __attribute__((ext_vector_type(4)));
typedef float f32x16 __attribute__((ext_vector_type(16)));
typedef u32 u32x2 __attribute__((ext_vector_type(2)));

#define DEV __device__ __forceinline__
#define INF __builtin_inff()
#define MFMA16(a, b, c) __builtin_amdgcn_mfma_f32_16x16x32_bf16((a), (b), (c), 0, 0, 0)
#define MFMA32(a, b, c) __builtin_amdgcn_mfma_f32_32x32x16_bf16((a), (b), (c), 0, 0, 0)
#define EXP2F(x) __builtin_amdgcn_exp2f(x)

// f32 -> bf16 round-to-nearest-even (bit version, for GEMM epilogues)
DEV u16 f2b(float f) {
  union { float f; unsigned u; } x; x.f = f;
  unsigned r = x.u + 0x7fffu + ((x.u >> 16) & 1u);
  return (u16)(r >> 16);
}

// pack two f32 into one u32 of 2 bf16 via native casts (compiler -> v_cvt_pk_bf16_f32)
DEV u32 pk2(float a, float b) {
  __bf16 lo = (__bf16)a, hi = (__bf16)b;
  u16 ul, uh;
  __builtin_memcpy(&ul, &lo, 2);
  __builtin_memcpy(&uh, &hi, 2);
  return (u32)ul | ((u32)uh << 16);
}

DEV float b2f(u16 v) {
  union { u32 u; float f; } x; x.u = (u32)v << 16; return x.f;
}

DEV void gl_lds16(const u16* g, u16* l) {
  __builtin_amdgcn_global_load_lds((const __attribute__((address_space(1))) void*)g,
                                   (__attribute__((address_space(3))) void*)l, 16, 0, 0);
}

// -------- fused f32 -> bf16 conversions (q + 4 weights) --------
__global__ __launch_bounds__(256) void cvt_all(const float* __restrict__ q,
                                               const float* __restrict__ wq,
                                               const float* __restrict__ wk,
                                               const float* __restrict__ wv,
                                               const float* __restrict__ wo,
                                               u16* __restrict__ xb, u16* __restrict__ wqb,
                                               u16* __restrict__ wkb, u16* __restrict__ wvb,
                                               u16* __restrict__ wob) {
  const int blk = blockIdx.x;
  const float* src; u16* dst; float scale = 1.f; int base;
  if (blk < 4096)      { src = q;  dst = xb;  base = blk; }
  else if (blk < 5120) { src = wq; dst = wqb; base = blk - 4096; scale = 0.045084441f; } // log2e/32
  else if (blk < 6144) { src = wk; dst = wkb; base = blk - 5120; }
  else if (blk < 7168) { src = wv; dst = wvb; base = blk - 6144; }
  else                 { src = wo; dst = wob; base = blk - 7168; }
  const int i = base * 256 + threadIdx.x;
  float4 v = reinterpret_cast<const float4*>(src)[i];
  ushort4 o;
  o.x = f2b(v.x * scale);
  o.y = f2b(v.y * scale);
  o.z = f2b(v.z * scale);
  o.w = f2b(v.w * scale);
  reinterpret_cast<ushort4*>(dst)[i] = o;
}

// ---------------- fused QKV projection GEMM + edge repack ----------------
// Blocks 0..511: one 64x128 A-tile of X, computing Q, K AND V outputs: per K-step
// stage A once + 3 W tiles, then 24 MFMAs/wave under ONE barrier pair (r19 had 16
// MFMA/step in 3 separate z-blocks: block-step count drops 24576->16384, and the
// per-step barrier drain -- the proven bottleneck, r17 -- amortizes 1.5x).
// Blocks 512..1535: edge repack (rides in spare HBM BW / block slots).
// LDS k-slot swizzle (both-sides): slot ^= (row>>1)&3 via pre-swizzled global
// source column + XOR on the read (r17: bank conflicts 3.1M -> 0).
__global__ __launch_bounds__(256, 2) void gemm_qkv3(const u16* __restrict__ X,
                                                    const u16* __restrict__ Wq,
                                                    const u16* __restrict__ Wk,
                                                    const u16* __restrict__ Wv,
                                                    u16* __restrict__ Yq, u16* __restrict__ Yk,
                                                    u16* __restrict__ Yv,
                                                    const float* __restrict__ edge,
                                                    u16* __restrict__ Ef) {
  __shared__ __attribute__((aligned(16))) u16 SA[2 * 2048];      // 2 bufs x 64x32
  __shared__ __attribute__((aligned(16))) u16 SB[3][2 * 4096];   // 3 x 2 bufs x 128x32
  const int id = blockIdx.x;
  const int t = threadIdx.x;

  if (id >= 512) {
    // ---- edge repack: [b][q][kv] f32 -> fragment-linear bf16 ----
    float (*Ls)[132] = reinterpret_cast<float(*)[132]>(&SB[0][0]);  // 16.9KB of SB
    const int rr = id - 512;             // 1024 blocks = (c:8, qt:32, b:4)
    const int c = rr & 7, qt = (rr >> 3) & 31, b = rr >> 8;
#pragma unroll
    for (int it = 0; it < 4; ++it) {
      int idx = it * 256 + t;
      int r = idx >> 5, k4 = idx & 31;
      f32x4 v = *reinterpret_cast<const f32x4*>(
          edge + (size_t)(b * 1024 + qt * 32 + r) * 1024 + c * 128 + k4 * 4);
      *reinterpret_cast<f32x4*>(&Ls[r][k4 * 4]) = v;   // 16B-aligned (132*4=33*16)
    }
    __syncthreads();
#pragma unroll
    for (int it = 0; it < 2; ++it) {
      int slot = it * 256 + t;
      int kvtl = slot >> 7, i = (slot >> 6) & 1, lane = slot & 63;
      int qv = lane & 31, hi = lane >> 5;
      u16x8 o;
#pragma unroll
      for (int jp = 0; jp < 8; ++jp) {
        int j = i * 8 + jp;
        int kvl = (j & 3) + 8 * (j >> 2) + 4 * hi;
        o[jp] = f2b(Ls[qv][kvtl * 32 + kvl]);
      }
      *reinterpret_cast<u16x8*>(
          Ef + ((size_t)(b * 32 + qt) * 32 + (c * 4 + kvtl)) * 1024 + i * 512 + lane * 8) = o;
    }
    return;
  }

  // ---- fused QKV GEMM: 64x128 tile, XCD-bijective (512 = 8*64, bx fastest) ----
  const int swz = (id & 7) * 64 + (id >> 3);
  const int by = swz >> 3, bx = swz & 7;
  const int m0 = by * 64, n0 = bx * 128;
  const int lane = t & 63, w = t >> 6;
  const int lr = lane & 15, lg = lane >> 4;
  const int wr = w >> 1, wc = w & 1;           // wave grid 2x2: 32 rows x 64 cols

  f32x4 acc[3][2][4] = {};

  const int r0 = t >> 2;                        // 0..63
  const int xw = (r0 >> 1) & 3;
  const int c0 = (((t & 3) ^ xw)) * 8;          // pre-swizzled global k-chunk
  const int xa = (lr >> 1) & 3;
  const u16* gA = X + (size_t)(m0 + r0) * 1024 + c0;
  const u16* gQ = Wq + (size_t)(n0 + r0) * 1024 + c0;
  const u16* gK = Wk + (size_t)(n0 + r0) * 1024 + c0;
  const u16* gV = Wv + (size_t)(n0 + r0) * 1024 + c0;

  auto stage = [&](int buf, int kt) {
    const int ko = kt * 32;
    gl_lds16(gA + ko, SA + buf * 2048 + w * 512);
    u16* lq = SB[0] + buf * 4096 + w * 512;
    u16* lk = SB[1] + buf * 4096 + w * 512;
    u16* lv = SB[2] + buf * 4096 + w * 512;
    gl_lds16(gQ + ko, lq);
    gl_lds16(gQ + ko + 64 * 1024, lq + 2048);
    gl_lds16(gK + ko, lk);
    gl_lds16(gK + ko + 64 * 1024, lk + 2048);
    gl_lds16(gV + ko, lv);
    gl_lds16(gV + ko + 64 * 1024, lv + 2048);
  };

  stage(0, 0);
  __syncthreads();
  for (int kt = 0; kt < 32; ++kt) {
    const int cur = kt & 1;
    if (kt < 31) stage(cur ^ 1, kt + 1);   // prefetch next tile (lands under MFMAs)
    const u16* As = SA + cur * 2048;
    b16x8 af[2];
#pragma unroll
    for (int m = 0; m < 2; ++m)
      af[m] = *reinterpret_cast<const b16x8*>(As + (wr * 32 + m * 16 + lr) * 32 + ((lg ^ xa) * 8));
#pragma unroll
    for (int z = 0; z < 3; ++z) {
      const u16* Bs = SB[z] + cur * 4096;
      b16x8 bf[4];
#pragma unroll
      for (int n = 0; n < 4; ++n)
        bf[n] = *reinterpret_cast<const b16x8*>(Bs + (wc * 64 + n * 16 + lr) * 32 + ((lg ^ xa) * 8));
#pragma unroll
      for (int m = 0; m < 2; ++m)
#pragma unroll
        for (int n = 0; n < 4; ++n)
          acc[z][m][n] = MFMA16(af[m], bf[n], acc[z][m][n]);
    }
    __syncthreads();   // drains prefetch (vmcnt0) + orders buffer reuse
  }

  // epilogues: z=0 Q, z=1 K (fragment-linear), z=2 V (sigma-permuted fragment)
#pragma unroll
  for (int z = 0; z < 3; ++z) {
    u16* Y = (z == 0) ? Yq : (z == 1) ? Yk : Yv;
#pragma unroll
    for (int m = 0; m < 2; ++m) {
      const int row = m0 + wr * 32 + m * 16 + lg * 4;
#pragma unroll
      for (int n = 0; n < 4; ++n) {
        const int col = n0 + wc * 64 + n * 16 + lr;
#pragma unroll
        for (int r = 0; r < 4; ++r) {
          const int rowg = row + r;
          const float v = acc[z][m][n][r];
          if (z < 2) {
            // Q/K fragment: lane=(row&31)+32*hi, k=s*16+hi*8+j
            const int bb = rowg >> 10, rw = rowg & 1023, rt = rw >> 5, rl = rw & 31;
            const int h = col >> 6, dh = col & 63;
            const int s = dh >> 4, hi = (dh >> 3) & 1, j = dh & 7;
            size_t idx = (((size_t)((bb * 16 + h) * 32 + rt) * 4 + s) * 64 + (rl + (hi << 5))) * 8 + j;
            Y[idx] = f2b(v);
          } else {
            // V fragment, sigma-permuted (swap bit2<->bit3 of kvl16)
            const int bb = rowg >> 10, kv = rowg & 1023, kvt = kv >> 5, kvl = kv & 31;
            const int s = kvl >> 4, k16 = kvl & 15;
            const int hi = (k16 >> 2) & 1;
            const int j = (k16 & 3) | (((k16 >> 3) & 1) << 2);
            const int h = col >> 6, dh = col & 63, d = dh >> 5;
            size_t idx = ((((size_t)((bb * 16 + h) * 32 + kvt) * 2 + d) * 2 + s) * 64 + ((dh & 31) + (hi << 5))) * 8 + j;
            Y[idx] = f2b(v);
          }
        }
      }
    }
  }
}

// ---------------- final GEMM: 64x128 tiles, 512 blocks = 2/CU ----------------
__global__ __launch_bounds__(256, 4) void gemm_final64(const u16* __restrict__ A,
                                                       const u16* __restrict__ Wo,
                                                       float* __restrict__ Out,
                                                       const float* __restrict__ bias,
                                                       const int* __restrict__ qmask) {
  __shared__ __attribute__((aligned(16))) u16 SA[2 * 2048];   // 2 bufs x 64x32
  __shared__ __attribute__((aligned(16))) u16 SB[2 * 4096];   // 2 bufs x 128x32
  const int id = blockIdx.x;
  const int swz = (id & 7) * 64 + (id >> 3);   // 512 = 8*64, bijective
  const int by = swz >> 3, bx = swz & 7;
  const int m0 = by * 64, n0 = bx * 128;
  const int t = threadIdx.x;
  const int lane = t & 63, w = t >> 6;
  const int lr = lane & 15, lg = lane >> 4;
  const int wr = w >> 1, wc = w & 1;           // wave grid 2x2: 32 rows x 64 cols each

  f32x4 acc[2][4] = {};

  const int r0 = t >> 2;                        // 0..63
  const int xw = (r0 >> 1) & 3;
  const int c0 = (((t & 3) ^ xw)) * 8;
  const int xa = (lr >> 1) & 3;
  const u16* gA = A + (size_t)(m0 + r0) * 1024 + c0;
  const u16* gB = Wo + (size_t)(n0 + r0) * 1024 + c0;

  auto stage = [&](int buf, int kt) {
    const int ko = kt * 32;
    u16* lA = SA + buf * 2048 + w * 512;
    u16* lB = SB + buf * 4096 + w * 512;
    gl_lds16(gA + ko, lA);                      // A rows 0..63 (one shot)
    gl_lds16(gB + ko, lB);                      // B rows 0..63
    gl_lds16(gB + ko + 64 * 1024, lB + 2048);   // B rows 64..127
  };

  stage(0, 0);
  __syncthreads();
  for (int kt = 0; kt < 32; ++kt) {
    const int cur = kt & 1;
    if (kt < 31) stage(cur ^ 1, kt + 1);
    const u16* As = SA + cur * 2048;
    const u16* Bs = SB + cur * 4096;
    b16x8 af[2], bf[4];
#pragma unroll
    for (int m = 0; m < 2; ++m)
      af[m] = *reinterpret_cast<const b16x8*>(As + (wr * 32 + m * 16 + lr) * 32 + ((lg ^ xa) * 8));
#pragma unroll
    for (int n = 0; n < 4; ++n)
      bf[n] = *reinterpret_cast<const b16x8*>(Bs + (wc * 64 + n * 16 + lr) * 32 + ((lg ^ xa) * 8));
#pragma unroll
    for (int m = 0; m < 2; ++m)
#pragma unroll
      for (int n = 0; n < 4; ++n)
        acc[m][n] = MFMA16(af[m], bf[n], acc[m][n]);
    __syncthreads();
  }

#pragma unroll
  for (int m = 0; m < 2; ++m) {
    const int row = m0 + wr * 32 + m * 16 + lg * 4;
#pragma unroll
    for (int n = 0; n < 4; ++n) {
      const int col = n0 + wc * 64 + n * 16 + lr;
#pragma unroll
      for (int r = 0; r < 4; ++r) {
        float y = acc[m][n][r] + bias[col];
        Out[(size_t)(row + r) * 1024 + col] = qmask[row + r] ? y : 0.f;
      }
    }
  }
}

// ---------------- fused attention: single stream/wave, E depth-3 ----------------
// No online max (scores bounded; masked -> exp2(-inf) = +0). E (zero-reuse, HBM-
// latency ~900cy) prefetched at DEPTH 3 via 4-buffer rotation; K depth 1 (L2-hot);
// V at compute start (L2-hot). Mask = LDS bf16 table. Q fragment-linear.
// (256,2) bound: (256,3) caps allocator at 84 VGPR -> ~35MB spill (r12);
// dual-stream ILP-2 at (256,1) -> 172 VGPR, occupancy 10%, 47us (r15).
__global__ __launch_bounds__(256, 2) void attn_kernel(
    const u16* __restrict__ Qf, const u16* __restrict__ Kf,
    const u16* __restrict__ Vf, const u16* __restrict__ Ef,
    const int* __restrict__ kvm, u16* __restrict__ out) {
  __shared__ float Osh[3][64][33];       // waves 1..3 partial O (pad 33: conflict-free)
  __shared__ float Lsh[4][32];
  __shared__ __attribute__((aligned(16))) u16 Fsh[1024];  // [kvt][hi][16] bf16 mask

  // XCD-bijective swizzle: 2048 blocks = 8 XCDs x 256; each XCD gets 8 bh x all 32 qt.
  const int d0 = blockIdx.x;
  const int logical = (d0 & 7) * 256 + (d0 >> 3);
  const int qt = logical & 31, bh = logical >> 5;
  const int b = bh >> 4, h = bh & 15;
  const int tid = threadIdx.x, lane = tid & 63, w = tid >> 6;
  const int ql = lane & 31, hi = lane >> 5;
  const int qrow = qt * 32 + ql;

  // build bf16 additive mask table: Fsh[kvt*32 + hi*16 + j]
#pragma unroll
  for (int e = 0; e < 4; ++e) {
    int idx = tid * 4 + e;
    int kt = idx >> 5, h2 = (idx >> 4) & 1, j = idx & 15;
    int kv = kt * 32 + 8 * (j >> 2) + 4 * h2 + (j & 3);
    Fsh[idx] = kvm[b * 1024 + kv] ? (u16)0 : (u16)0xFF80;  // 0 or -inf (bf16)
  }

  // Q fragments (fragment-linear, coalesced: same mapping as K)
  const u16* qp = Qf + (size_t)bh * 65536 + qt * 2048 + lane * 8;
  b16x8 Qr[4];
#pragma unroll
  for (int s = 0; s < 4; ++s) Qr[s] = *reinterpret_cast<const b16x8*>(qp + s * 512);

  const u16* kp = Kf + (size_t)bh * 65536 + lane * 8;
  const u16* vp = Vf + (size_t)bh * 65536 + lane * 8;
  const u16* ep = Ef + (size_t)(b * 32 + qt) * 32768 + lane * 8;

  f32x16 O0 = {}, O1 = {};
  float La[4] = {};

  struct KB { b16x8 K[4]; };
  struct EB { u16x8 E[2]; };
  KB Ka, Kb;
  EB E0, E1, E2, E3;

  auto fK = [&](KB& T, int kvt) {
#pragma unroll
    for (int s = 0; s < 4; ++s)
      T.K[s] = *reinterpret_cast<const b16x8*>(kp + kvt * 2048 + s * 512);
  };
  auto fE = [&](EB& T, int kvt) {
#pragma unroll
    for (int i = 0; i < 2; ++i)
      T.E[i] = *reinterpret_cast<const u16x8*>(ep + kvt * 1024 + i * 512);
  };

  auto compute = [&](const KB& K, const EB& E, int kvt) {
    // V single-buffer: issued here, consumed ~400cyc later in PV (L2-hot)
    b16x8 V[4];
#pragma unroll
    for (int ds = 0; ds < 4; ++ds)
      V[ds] = *reinterpret_cast<const b16x8*>(vp + kvt * 2048 + ds * 512);
    // mask: 2 broadcast LDS reads
    u16x8 Fm0 = *reinterpret_cast<const u16x8*>(&Fsh[kvt * 32 + hi * 16]);
    u16x8 Fm1 = *reinterpret_cast<const u16x8*>(&Fsh[kvt * 32 + hi * 16 + 8]);
    f32x16 S = {};
#pragma unroll
    for (int s = 0; s < 4; ++s) S = MFMA32(K.K[s], Qr[s], S);
    // p = exp2(S*edge + mask): masked -> -inf -> exp2 = +0 exactly
    float p[16];
#pragma unroll
    for (int j = 0; j < 8; ++j)
      p[j] = EXP2F(fmaf(S[j], b2f(E.E[0][j]), b2f(Fm0[j])));
#pragma unroll
    for (int j = 0; j < 8; ++j)
      p[8 + j] = EXP2F(fmaf(S[8 + j], b2f(E.E[1][j]), b2f(Fm1[j])));
#pragma unroll
    for (int j = 0; j < 16; ++j) La[j & 3] += p[j];
    // zero-shuffle PV: V is sigma-permuted, so own p[8s..8s+7] IS the B-operand.
#pragma unroll
    for (int s = 0; s < 2; ++s) {
      union { u32 wd[4]; b16x8 v; } U;
      U.wd[0] = pk2(p[8 * s + 0], p[8 * s + 1]);
      U.wd[1] = pk2(p[8 * s + 2], p[8 * s + 3]);
      U.wd[2] = pk2(p[8 * s + 4], p[8 * s + 5]);
      U.wd[3] = pk2(p[8 * s + 6], p[8 * s + 7]);
      O0 = MFMA32(V[s], U.v, O0);      // d 0..31
      O1 = MFMA32(V[2 + s], U.v, O1);  // d 32..63
    }
  };

  // per-wave kv quarter: 8 tiles; E depth 3 (4-buf), K depth 1 (2-buf), V depth 0.
  const int base = w * 8;
  fE(E0, base); fE(E1, base + 1); fE(E2, base + 2);
  fK(Ka, base);
  __syncthreads();                       // Fsh ready (fetches overlap the build)

  fE(E3, base + 3); fK(Kb, base + 1); compute(Ka, E0, base + 0);
  fE(E0, base + 4); fK(Ka, base + 2); compute(Kb, E1, base + 1);
  fE(E1, base + 5); fK(Kb, base + 3); compute(Ka, E2, base + 2);
  fE(E2, base + 6); fK(Ka, base + 4); compute(Kb, E3, base + 3);
  fE(E3, base + 7); fK(Kb, base + 5); compute(Ka, E0, base + 4);
                    fK(Ka, base + 6); compute(Kb, E1, base + 5);
                    fK(Kb, base + 7); compute(Ka, E2, base + 6);
                                      compute(Kb, E3, base + 7);

  // wave-local L
  float Lw = (La[0] + La[1]) + (La[2] + La[3]);
  Lw += __shfl_xor(Lw, 32, 64);

  // ---- merge across the 4 kv-quarters (pure sums; no max machinery) ----
  if (hi == 0) Lsh[w][ql] = Lw;
  if (w > 0) {
#pragma unroll
    for (int r = 0; r < 16; ++r) Osh[w - 1][lane][r] = O0[r];
#pragma unroll
    for (int r = 0; r < 16; ++r) Osh[w - 1][lane][16 + r] = O1[r];
  }
  __syncthreads();
  if (w == 0) {
    float Lg = (Lsh[0][ql] + Lsh[1][ql]) + (Lsh[2][ql] + Lsh[3][ql]);
#pragma unroll
    for (int wv = 0; wv < 3; ++wv) {
#pragma unroll
      for (int r = 0; r < 16; ++r) O0[r] += Osh[wv][lane][r];
#pragma unroll
      for (int r = 0; r < 16; ++r) O1[r] += Osh[wv][lane][16 + r];
    }
    const float inv = (Lg > 0.f) ? 1.f / Lg : 0.f;
    u16* orow = out + (size_t)(b * 1024 + qrow) * 1024 + h * 64 + hi * 4;
#pragma unroll
    for (int H = 0; H < 2; ++H) {
#pragma unroll
      for (int g = 0; g < 4; ++g) {
        float o0 = (H ? O1[4 * g + 0] : O0[4 * g + 0]) * inv;
        float o1 = (H ? O1[4 * g + 1] : O0[4 * g + 1]) * inv;
        float o2 = (H ? O1[4 * g + 2] : O0[4 * g + 2]) * inv;
        float o3 = (H ? O1[4 * g + 3] : O0[4 * g + 3]) * inv;
        u32x2 wv2 = {pk2(o0, o1), pk2(o2, o3)};
        *reinterpret_cast<u32x2*>(orow + H * 32 + g * 8) = wv2;
      }
    }
  }
}

// ---------------- launch ----------------
extern "C" void kernel_launch(void* const* d_in, const int* in_sizes, int n_in,
                              void* d_out, int out_size, void* d_ws, size_t ws_size,
                              hipStream_t stream) {
  (void)in_sizes; (void)n_in; (void)out_size; (void)ws_size;
  const float* q    = (const float*)d_in[0];
  const int*   qm   = (const int*)d_in[1];
  const int*   kvm  = (const int*)d_in[2];
  const float* edge = (const float*)d_in[3];
  const float* wq   = (const float*)d_in[4];
  const float* wk   = (const float*)d_in[5];
  const float* wv   = (const float*)d_in[6];
  const float* wo   = (const float*)d_in[7];
  const float* bo   = (const float*)d_in[8];
  float* out = (float*)d_out;

  char* ws = (char*)d_ws;
  u16* xb  = (u16*)(ws);                       // 8MB  X bf16; dead after gemm_qkv3
  u16* wqb = (u16*)(ws + (8ull  << 20));       // 2MB; read only by gemm_qkv3
  u16* wkb = (u16*)(ws + (10ull << 20));       // 2MB; read only by gemm_qkv3
  u16* wvb = (u16*)(ws + (12ull << 20));       // 2MB; read only by gemm_qkv3
  u16* wob = (u16*)(ws + (14ull << 20));       // 2MB; read by gemm_final64
  u16* Qfb = (u16*)(ws + (16ull << 20));       // 8MB Q fragment-linear (scaled log2e/32)
  u16* Kf  = (u16*)(ws + (24ull << 20));       // 8MB K fragment-linear
  u16* Vf  = (u16*)(ws + (32ull << 20));       // 8MB V fragment-linear (sigma-permuted)
  u16* Ef  = (u16*)(ws + (40ull << 20));       // 8MB edge fragment-linear bf16
  u16* ab  = xb;                               // attn out -> xb (last xb read precedes)

  cvt_all<<<8192, 256, 0, stream>>>(q, wq, wk, wv, wo, xb, wqb, wkb, wvb, wob);
  gemm_qkv3<<<1536, 256, 0, stream>>>(xb, wqb, wkb, wvb, Qfb, Kf, Vf, edge, Ef);
  attn_kernel<<<2048, 256, 0, stream>>>(Qfb, Kf, Vf, Ef, kvm, ab);
  gemm_final64<<<512, 256, 0, stream>>>(ab, wob, out, bo, qm);
}

// Round 21
// 104.234 us; speedup vs baseline: 1.0846x; 1.0846x over previous
//
#include <hip/hip_runtime.h>

typedef unsigned short u16;
typedef unsigned int u32;
typedef __bf16 b16x8 __attribute__((ext_vector_type(8)));
typedef u16 u16x8 __attribute__((ext_vector_type(8)));
typedef float f32x4 __attribute__((ext_vector_type(4)));
typedef float f32x16 __attribute__((ext_vector_type(16)));
typedef u32 u32x2 __attribute__((ext_vector_type(2)));

#define DEV __device__ __forceinline__
#define INF __builtin_inff()
#define MFMA16(a, b, c) __builtin_amdgcn_mfma_f32_16x16x32_bf16((a), (b), (c), 0, 0, 0)
#define MFMA32(a, b, c) __builtin_amdgcn_mfma_f32_32x32x16_bf16((a), (b), (c), 0, 0, 0)
#define EXP2F(x) __builtin_amdgcn_exp2f(x)

// f32 -> bf16 round-to-nearest-even (bit version, for GEMM epilogues)
DEV u16 f2b(float f) {
  union { float f; unsigned u; } x; x.f = f;
  unsigned r = x.u + 0x7fffu + ((x.u >> 16) & 1u);
  return (u16)(r >> 16);
}

// pack two f32 into one u32 of 2 bf16 via native casts (compiler -> v_cvt_pk_bf16_f32)
DEV u32 pk2(float a, float b) {
  __bf16 lo = (__bf16)a, hi = (__bf16)b;
  u16 ul, uh;
  __builtin_memcpy(&ul, &lo, 2);
  __builtin_memcpy(&uh, &hi, 2);
  return (u32)ul | ((u32)uh << 16);
}

DEV float b2f(u16 v) {
  union { u32 u; float f; } x; x.u = (u32)v << 16; return x.f;
}

DEV void gl_lds16(const u16* g, u16* l) {
  __builtin_amdgcn_global_load_lds((const __attribute__((address_space(1))) void*)g,
                                   (__attribute__((address_space(3))) void*)l, 16, 0, 0);
}

// -------- fused f32 -> bf16 conversions (q + 4 weights) --------
__global__ __launch_bounds__(256) void cvt_all(const float* __restrict__ q,
                                               const float* __restrict__ wq,
                                               const float* __restrict__ wk,
                                               const float* __restrict__ wv,
                                               const float* __restrict__ wo,
                                               u16* __restrict__ xb, u16* __restrict__ wqb,
                                               u16* __restrict__ wkb, u16* __restrict__ wvb,
                                               u16* __restrict__ wob) {
  const int blk = blockIdx.x;
  const float* src; u16* dst; float scale = 1.f; int base;
  if (blk < 4096)      { src = q;  dst = xb;  base = blk; }
  else if (blk < 5120) { src = wq; dst = wqb; base = blk - 4096; scale = 0.045084441f; } // log2e/32
  else if (blk < 6144) { src = wk; dst = wkb; base = blk - 5120; }
  else if (blk < 7168) { src = wv; dst = wvb; base = blk - 6144; }
  else                 { src = wo; dst = wob; base = blk - 7168; }
  const int i = base * 256 + threadIdx.x;
  float4 v = reinterpret_cast<const float4*>(src)[i];
  ushort4 o;
  o.x = f2b(v.x * scale);
  o.y = f2b(v.y * scale);
  o.z = f2b(v.z * scale);
  o.w = f2b(v.w * scale);
  reinterpret_cast<ushort4*>(dst)[i] = o;
}

// ---------------- GEMM body: Y[M,1024] = A[M,1024] @ W[1024,1024]^T ----------------
// 2-phase prefetch; shared LDS from wrapper; m0/n0 from wrapper (XCD swizzle).
// LDS k-slot swizzle (both-sides): slot ^= (row>>1)&3 via pre-swizzled global
// source column + XOR on the read (r17: bank conflicts 3.1M -> 0).
// MODE 1: Q/K fragment-linear. MODE 2: V fragment-linear (sigma-permuted).
template <int MODE>
DEV void gemm_body(u16* __restrict__ SA, u16* __restrict__ SB, int m0, int n0,
                   const u16* __restrict__ A, const u16* __restrict__ W,
                   u16* __restrict__ Ybf) {
  const int t = threadIdx.x;
  const int lane = t & 63, w = t >> 6;
  const int lr = lane & 15, lg = lane >> 4;
  const int wr = w >> 1, wc = w & 1;

  f32x4 acc[4][4] = {};

  const int r0 = t >> 2;
  const int xw = (r0 >> 1) & 3;                  // write-side swizzle (const/thread)
  const int c0 = (((t & 3) ^ xw)) * 8;           // pre-swizzled global k-chunk
  const int xa = (lr >> 1) & 3;                  // read-side swizzle (const/thread)
  const u16* gA = A + (size_t)(m0 + r0) * 1024 + c0;
  const u16* gB = W + (size_t)(n0 + r0) * 1024 + c0;

  auto stage = [&](int buf, int kt) {
    const int ko = kt * 32;
    u16* lA = SA + buf * 4096 + w * 512;
    u16* lB = SB + buf * 4096 + w * 512;
    gl_lds16(gA + ko, lA);
    gl_lds16(gA + ko + 64 * 1024, lA + 2048);
    gl_lds16(gB + ko, lB);
    gl_lds16(gB + ko + 64 * 1024, lB + 2048);
  };

  stage(0, 0);
  __syncthreads();
  for (int kt = 0; kt < 32; ++kt) {
    const int cur = kt & 1;
    if (kt < 31) stage(cur ^ 1, kt + 1);   // prefetch next tile (lands under MFMAs)
    const u16* As = SA + cur * 4096;
    const u16* Bs = SB + cur * 4096;
    b16x8 af[4], bf[4];
#pragma unroll
    for (int m = 0; m < 4; ++m)
      af[m] = *reinterpret_cast<const b16x8*>(As + (wr * 64 + m * 16 + lr) * 32 + ((lg ^ xa) * 8));
#pragma unroll
    for (int n = 0; n < 4; ++n)
      bf[n] = *reinterpret_cast<const b16x8*>(Bs + (wc * 64 + n * 16 + lr) * 32 + ((lg ^ xa) * 8));
#pragma unroll
    for (int m = 0; m < 4; ++m)
#pragma unroll
      for (int n = 0; n < 4; ++n)
        acc[m][n] = MFMA16(af[m], bf[n], acc[m][n]);
    __syncthreads();   // drains prefetch (vmcnt0) + orders buffer reuse
  }

#pragma unroll
  for (int m = 0; m < 4; ++m) {
    const int row = m0 + wr * 64 + m * 16 + lg * 4;
#pragma unroll
    for (int n = 0; n < 4; ++n) {
      const int col = n0 + wc * 64 + n * 16 + lr;
#pragma unroll
      for (int r = 0; r < 4; ++r) {
        const int rowg = row + r;
        const float v = acc[m][n][r];
        if (MODE == 1) {
          // Q/K fragment: value = X[b][row][h*64+dh]; lane=(row&31)+32*hi, k=s*16+hi*8+j
          const int bb = rowg >> 10, rw = rowg & 1023, rt = rw >> 5, rl = rw & 31;
          const int h = col >> 6, dh = col & 63;
          const int s = dh >> 4, hi = (dh >> 3) & 1, j = dh & 7;
          size_t idx = (((size_t)((bb * 16 + h) * 32 + rt) * 4 + s) * 64 + (rl + (hi << 5))) * 8 + j;
          Ybf[idx] = f2b(v);
        } else {
          // V fragment, sigma-permuted (swap bit2<->bit3 of kvl16): PV B-operand
          // becomes lane-local: hi=(kvl>>2)&1, j=(kvl&3)|(((kvl>>3)&1)<<2).
          const int bb = rowg >> 10, kv = rowg & 1023, kvt = kv >> 5, kvl = kv & 31;
          const int s = kvl >> 4, k16 = kvl & 15;
          const int hi = (k16 >> 2) & 1;
          const int j = (k16 & 3) | (((k16 >> 3) & 1) << 2);
          const int h = col >> 6, dh = col & 63, d = dh >> 5;
          size_t idx = ((((size_t)((bb * 16 + h) * 32 + kvt) * 2 + d) * 2 + s) * 64 + ((dh & 31) + (hi << 5))) * 8 + j;
          Ybf[idx] = f2b(v);
        }
      }
    }
  }
}

// gemm_qkv + fused edge repack. Blocks 0..767: GEMM (8 XCDs x 96-chunk bijective,
// bx fastest -> A panel L2-shared). Blocks 768..1791: edge repack (rides in the
// spare block slot / HBM shadow of the GEMM: gemm uses 3 of 4 block slots and
// ~15% of HBM BW). One 32KB LDS union serves both paths.
__global__ __launch_bounds__(256, 4) void gemm_qkv(const u16* __restrict__ X,
                                                   const u16* __restrict__ Wq,
                                                   const u16* __restrict__ Wk,
                                                   const u16* __restrict__ Wv,
                                                   u16* __restrict__ Yq, u16* __restrict__ Yk,
                                                   u16* __restrict__ Yv,
                                                   const float* __restrict__ edge,
                                                   u16* __restrict__ Ef) {
  __shared__ __attribute__((aligned(16))) u16 SU[4 * 4096];   // 32KB union
  const int id = blockIdx.x;
  const int tid = threadIdx.x;
  if (id >= 768) {
    // ---- edge repack: [b][q][kv] f32 -> fragment-linear bf16 ----
    float (*Ls)[132] = reinterpret_cast<float(*)[132]>(SU);   // 16.9KB of the union
    const int rr = id - 768;             // 1024 blocks = (c:8, qt:32, b:4)
    const int c = rr & 7, qt = (rr >> 3) & 31, b = rr >> 8;
#pragma unroll
    for (int it = 0; it < 4; ++it) {
      int idx = it * 256 + tid;
      int r = idx >> 5, k4 = idx & 31;
      f32x4 v = *reinterpret_cast<const f32x4*>(
          edge + (size_t)(b * 1024 + qt * 32 + r) * 1024 + c * 128 + k4 * 4);
      *reinterpret_cast<f32x4*>(&Ls[r][k4 * 4]) = v;   // 16B-aligned (132*4=33*16)
    }
    __syncthreads();
#pragma unroll
    for (int it = 0; it < 2; ++it) {
      int slot = it * 256 + tid;
      int kvtl = slot >> 7, i = (slot >> 6) & 1, lane = slot & 63;
      int qv = lane & 31, hi = lane >> 5;
      u16x8 o;
#pragma unroll
      for (int jp = 0; jp < 8; ++jp) {
        int j = i * 8 + jp;
        int kvl = (j & 3) + 8 * (j >> 2) + 4 * hi;
        o[jp] = f2b(Ls[qv][kvtl * 32 + kvl]);
      }
      *reinterpret_cast<u16x8*>(
          Ef + ((size_t)(b * 32 + qt) * 32 + (c * 4 + kvtl)) * 1024 + i * 512 + lane * 8) = o;
    }
    return;
  }
  u16* SA = SU;
  u16* SB = SU + 2 * 4096;
  const int swz = (id & 7) * 96 + (id >> 3);   // 768 = 8*96, bijective
  const int z = swz >> 8, rem = swz & 255;
  const int by = rem >> 3, bx = rem & 7;
  const int m0 = by * 128, n0 = bx * 128;
  if (z == 0)      gemm_body<1>(SA, SB, m0, n0, X, Wq, Yq);
  else if (z == 1) gemm_body<1>(SA, SB, m0, n0, X, Wk, Yk);
  else             gemm_body<2>(SA, SB, m0, n0, X, Wv, Yv);
}

// ---------------- final GEMM: 64x128 tiles, 512 blocks = 2/CU ----------------
// 128x128 grid was 256 blocks = exactly 1 block/CU: the 2-phase prefetch had NO
// co-resident block to overlap the per-K-step barrier drain. 64x128 halves
// per-block work -> 2 balanced blocks/CU. Same swizzles/arithmetic.
__global__ __launch_bounds__(256, 4) void gemm_final64(const u16* __restrict__ A,
                                                       const u16* __restrict__ Wo,
                                                       float* __restrict__ Out,
                                                       const float* __restrict__ bias,
                                                       const int* __restrict__ qmask) {
  __shared__ __attribute__((aligned(16))) u16 SA[2 * 2048];   // 2 bufs x 64x32
  __shared__ __attribute__((aligned(16))) u16 SB[2 * 4096];   // 2 bufs x 128x32
  const int id = blockIdx.x;
  const int swz = (id & 7) * 64 + (id >> 3);   // 512 = 8*64, bijective
  const int by = swz >> 3, bx = swz & 7;
  const int m0 = by * 64, n0 = bx * 128;
  const int t = threadIdx.x;
  const int lane = t & 63, w = t >> 6;
  const int lr = lane & 15, lg = lane >> 4;
  const int wr = w >> 1, wc = w & 1;           // wave grid 2x2: 32 rows x 64 cols each

  f32x4 acc[2][4] = {};

  const int r0 = t >> 2;                        // 0..63
  const int xw = (r0 >> 1) & 3;
  const int c0 = (((t & 3) ^ xw)) * 8;
  const int xa = (lr >> 1) & 3;
  const u16* gA = A + (size_t)(m0 + r0) * 1024 + c0;
  const u16* gB = Wo + (size_t)(n0 + r0) * 1024 + c0;

  auto stage = [&](int buf, int kt) {
    const int ko = kt * 32;
    u16* lA = SA + buf * 2048 + w * 512;
    u16* lB = SB + buf * 4096 + w * 512;
    gl_lds16(gA + ko, lA);                      // A rows 0..63 (one shot)
    gl_lds16(gB + ko, lB);                      // B rows 0..63
    gl_lds16(gB + ko + 64 * 1024, lB + 2048);   // B rows 64..127
  };

  stage(0, 0);
  __syncthreads();
  for (int kt = 0; kt < 32; ++kt) {
    const int cur = kt & 1;
    if (kt < 31) stage(cur ^ 1, kt + 1);
    const u16* As = SA + cur * 2048;
    const u16* Bs = SB + cur * 4096;
    b16x8 af[2], bf[4];
#pragma unroll
    for (int m = 0; m < 2; ++m)
      af[m] = *reinterpret_cast<const b16x8*>(As + (wr * 32 + m * 16 + lr) * 32 + ((lg ^ xa) * 8));
#pragma unroll
    for (int n = 0; n < 4; ++n)
      bf[n] = *reinterpret_cast<const b16x8*>(Bs + (wc * 64 + n * 16 + lr) * 32 + ((lg ^ xa) * 8));
#pragma unroll
    for (int m = 0; m < 2; ++m)
#pragma unroll
      for (int n = 0; n < 4; ++n)
        acc[m][n] = MFMA16(af[m], bf[n], acc[m][n]);
    __syncthreads();
  }

#pragma unroll
  for (int m = 0; m < 2; ++m) {
    const int row = m0 + wr * 32 + m * 16 + lg * 4;
#pragma unroll
    for (int n = 0; n < 4; ++n) {
      const int col = n0 + wc * 64 + n * 16 + lr;
#pragma unroll
      for (int r = 0; r < 4; ++r) {
        float y = acc[m][n][r] + bias[col];
        Out[(size_t)(row + r) * 1024 + col] = qmask[row + r] ? y : 0.f;
      }
    }
  }
}

// ---------------- fused attention: single stream/wave, E depth-3 ----------------
// No online max (scores bounded; masked -> exp2(-inf) = +0). E (zero-reuse, HBM-
// latency ~900cy) prefetched at DEPTH 3 via 4-buffer rotation; K depth 1 (L2-hot);
// V at compute start (L2-hot). Mask = LDS bf16 table. Q fragment-linear.
// (256,2) bound: (256,3) caps allocator at 84 VGPR -> ~35MB spill (r12);
// dual-stream ILP-2 at (256,1) -> 172 VGPR, occupancy 10%, 47us (r15).
__global__ __launch_bounds__(256, 2) void attn_kernel(
    const u16* __restrict__ Qf, const u16* __restrict__ Kf,
    const u16* __restrict__ Vf, const u16* __restrict__ Ef,
    const int* __restrict__ kvm, u16* __restrict__ out) {
  __shared__ float Osh[3][64][33];       // waves 1..3 partial O (pad 33: conflict-free)
  __shared__ float Lsh[4][32];
  __shared__ __attribute__((aligned(16))) u16 Fsh[1024];  // [kvt][hi][16] bf16 mask

  // XCD-bijective swizzle: 2048 blocks = 8 XCDs x 256; each XCD gets 8 bh x all 32 qt.
  const int d0 = blockIdx.x;
  const int logical = (d0 & 7) * 256 + (d0 >> 3);
  const int qt = logical & 31, bh = logical >> 5;
  const int b = bh >> 4, h = bh & 15;
  const int tid = threadIdx.x, lane = tid & 63, w = tid >> 6;
  const int ql = lane & 31, hi = lane >> 5;
  const int qrow = qt * 32 + ql;

  // build bf16 additive mask table: Fsh[kvt*32 + hi*16 + j]
#pragma unroll
  for (int e = 0; e < 4; ++e) {
    int idx = tid * 4 + e;
    int kt = idx >> 5, h2 = (idx >> 4) & 1, j = idx & 15;
    int kv = kt * 32 + 8 * (j >> 2) + 4 * h2 + (j & 3);
    Fsh[idx] = kvm[b * 1024 + kv] ? (u16)0 : (u16)0xFF80;  // 0 or -inf (bf16)
  }

  // Q fragments (fragment-linear, coalesced: same mapping as K)
  const u16* qp = Qf + (size_t)bh * 65536 + qt * 2048 + lane * 8;
  b16x8 Qr[4];
#pragma unroll
  for (int s = 0; s < 4; ++s) Qr[s] = *reinterpret_cast<const b16x8*>(qp + s * 512);

  const u16* kp = Kf + (size_t)bh * 65536 + lane * 8;
  const u16* vp = Vf + (size_t)bh * 65536 + lane * 8;
  const u16* ep = Ef + (size_t)(b * 32 + qt) * 32768 + lane * 8;

  f32x16 O0 = {}, O1 = {};
  float La[4] = {};

  struct KB { b16x8 K[4]; };
  struct EB { u16x8 E[2]; };
  KB Ka, Kb;
  EB E0, E1, E2, E3;

  auto fK = [&](KB& T, int kvt) {
#pragma unroll
    for (int s = 0; s < 4; ++s)
      T.K[s] = *reinterpret_cast<const b16x8*>(kp + kvt * 2048 + s * 512);
  };
  auto fE = [&](EB& T, int kvt) {
#pragma unroll
    for (int i = 0; i < 2; ++i)
      T.E[i] = *reinterpret_cast<const u16x8*>(ep + kvt * 1024 + i * 512);
  };

  auto compute = [&](const KB& K, const EB& E, int kvt) {
    // V single-buffer: issued here, consumed ~400cyc later in PV (L2-hot)
    b16x8 V[4];
#pragma unroll
    for (int ds = 0; ds < 4; ++ds)
      V[ds] = *reinterpret_cast<const b16x8*>(vp + kvt * 2048 + ds * 512);
    // mask: 2 broadcast LDS reads
    u16x8 Fm0 = *reinterpret_cast<const u16x8*>(&Fsh[kvt * 32 + hi * 16]);
    u16x8 Fm1 = *reinterpret_cast<const u16x8*>(&Fsh[kvt * 32 + hi * 16 + 8]);
    f32x16 S = {};
#pragma unroll
    for (int s = 0; s < 4; ++s) S = MFMA32(K.K[s], Qr[s], S);
    // p = exp2(S*edge + mask): masked -> -inf -> exp2 = +0 exactly
    float p[16];
#pragma unroll
    for (int j = 0; j < 8; ++j)
      p[j] = EXP2F(fmaf(S[j], b2f(E.E[0][j]), b2f(Fm0[j])));
#pragma unroll
    for (int j = 0; j < 8; ++j)
      p[8 + j] = EXP2F(fmaf(S[8 + j], b2f(E.E[1][j]), b2f(Fm1[j])));
#pragma unroll
    for (int j = 0; j < 16; ++j) La[j & 3] += p[j];
    // zero-shuffle PV: V is sigma-permuted, so own p[8s..8s+7] IS the B-operand.
#pragma unroll
    for (int s = 0; s < 2; ++s) {
      union { u32 wd[4]; b16x8 v; } U;
      U.wd[0] = pk2(p[8 * s + 0], p[8 * s + 1]);
      U.wd[1] = pk2(p[8 * s + 2], p[8 * s + 3]);
      U.wd[2] = pk2(p[8 * s + 4], p[8 * s + 5]);
      U.wd[3] = pk2(p[8 * s + 6], p[8 * s + 7]);
      O0 = MFMA32(V[s], U.v, O0);      // d 0..31
      O1 = MFMA32(V[2 + s], U.v, O1);  // d 32..63
    }
  };

  // per-wave kv quarter: 8 tiles; E depth 3 (4-buf), K depth 1 (2-buf), V depth 0.
  const int base = w * 8;
  fE(E0, base); fE(E1, base + 1); fE(E2, base + 2);
  fK(Ka, base);
  __syncthreads();                       // Fsh ready (fetches overlap the build)

  fE(E3, base + 3); fK(Kb, base + 1); compute(Ka, E0, base + 0);
  fE(E0, base + 4); fK(Ka, base + 2); compute(Kb, E1, base + 1);
  fE(E1, base + 5); fK(Kb, base + 3); compute(Ka, E2, base + 2);
  fE(E2, base + 6); fK(Ka, base + 4); compute(Kb, E3, base + 3);
  fE(E3, base + 7); fK(Kb, base + 5); compute(Ka, E0, base + 4);
                    fK(Ka, base + 6); compute(Kb, E1, base + 5);
                    fK(Kb, base + 7); compute(Ka, E2, base + 6);
                                      compute(Kb, E3, base + 7);

  // wave-local L
  float Lw = (La[0] + La[1]) + (La[2] + La[3]);
  Lw += __shfl_xor(Lw, 32, 64);

  // ---- merge across the 4 kv-quarters (pure sums; no max machinery) ----
  if (hi == 0) Lsh[w][ql] = Lw;
  if (w > 0) {
#pragma unroll
    for (int r = 0; r < 16; ++r) Osh[w - 1][lane][r] = O0[r];
#pragma unroll
    for (int r = 0; r < 16; ++r) Osh[w - 1][lane][16 + r] = O1[r];
  }
  __syncthreads();
  if (w == 0) {
    float Lg = (Lsh[0][ql] + Lsh[1][ql]) + (Lsh[2][ql] + Lsh[3][ql]);
#pragma unroll
    for (int wv = 0; wv < 3; ++wv) {
#pragma unroll
      for (int r = 0; r < 16; ++r) O0[r] += Osh[wv][lane][r];
#pragma unroll
      for (int r = 0; r < 16; ++r) O1[r] += Osh[wv][lane][16 + r];
    }
    const float inv = (Lg > 0.f) ? 1.f / Lg : 0.f;
    u16* orow = out + (size_t)(b * 1024 + qrow) * 1024 + h * 64 + hi * 4;
#pragma unroll
    for (int H = 0; H < 2; ++H) {
#pragma unroll
      for (int g = 0; g < 4; ++g) {
        float o0 = (H ? O1[4 * g + 0] : O0[4 * g + 0]) * inv;
        float o1 = (H ? O1[4 * g + 1] : O0[4 * g + 1]) * inv;
        float o2 = (H ? O1[4 * g + 2] : O0[4 * g + 2]) * inv;
        float o3 = (H ? O1[4 * g + 3] : O0[4 * g + 3]) * inv;
        u32x2 wv2 = {pk2(o0, o1), pk2(o2, o3)};
        *reinterpret_cast<u32x2*>(orow + H * 32 + g * 8) = wv2;
      }
    }
  }
}

// ---------------- launch ----------------
extern "C" void kernel_launch(void* const* d_in, const int* in_sizes, int n_in,
                              void* d_out, int out_size, void* d_ws, size_t ws_size,
                              hipStream_t stream) {
  (void)in_sizes; (void)n_in; (void)out_size; (void)ws_size;
  const float* q    = (const float*)d_in[0];
  const int*   qm   = (const int*)d_in[1];
  const int*   kvm  = (const int*)d_in[2];
  const float* edge = (const float*)d_in[3];
  const float* wq   = (const float*)d_in[4];
  const float* wk   = (const float*)d_in[5];
  const float* wv   = (const float*)d_in[6];
  const float* wo   = (const float*)d_in[7];
  const float* bo   = (const float*)d_in[8];
  float* out = (float*)d_out;

  char* ws = (char*)d_ws;
  u16* xb  = (u16*)(ws);                       // 8MB  X bf16; dead after gemm_qkv
  u16* wqb = (u16*)(ws + (8ull  << 20));       // 2MB; read only by gemm_qkv
  u16* wkb = (u16*)(ws + (10ull << 20));       // 2MB; read only by gemm_qkv
  u16* wvb = (u16*)(ws + (12ull << 20));       // 2MB; read only by gemm_qkv
  u16* wob = (u16*)(ws + (14ull << 20));       // 2MB; read by gemm_final64
  u16* Qfb = (u16*)(ws + (16ull << 20));       // 8MB Q fragment-linear (scaled log2e/32)
  u16* Kf  = (u16*)(ws + (24ull << 20));       // 8MB K fragment-linear
  u16* Vf  = (u16*)(ws + (32ull << 20));       // 8MB V fragment-linear (sigma-permuted)
  u16* Ef  = (u16*)(ws + (40ull << 20));       // 8MB edge fragment-linear bf16
  u16* ab  = xb;                               // attn out -> xb (last xb read precedes)

  cvt_all<<<8192, 256, 0, stream>>>(q, wq, wk, wv, wo, xb, wqb, wkb, wvb, wob);
  gemm_qkv<<<1792, 256, 0, stream>>>(xb, wqb, wkb, wvb, Qfb, Kf, Vf, edge, Ef);
  attn_kernel<<<2048, 256, 0, stream>>>(Qfb, Kf, Vf, Ef, kvm, ab);
  gemm_final64<<<512, 256, 0, stream>>>(ab, wob, out, bo, qm);
}